// Round 18
// baseline (20.899 us; speedup 1.0000x reference)
//
#include <hip/hip_runtime.h>

// GrowingSignature: truncated iterated-sums signature, levels 1..4, F=4.
// x: (32, 512, 4) f32;  out: (32, 512, 341) f32.
// R17 winner + R18 changes, both aimed at serial latency in sigC:
//  (1) combine loop is constant-trip 15 (rows j>=c zero-filled AT STAGING,
//      one cndmask per float4, parallel) -> full unroll, LDS reads pipeline
//      off the FMA dependency chain (runtime-trip prevented this before);
//  (2) scan store-batching widened 4 -> 8 (store-source snapshot regs are
//      rewritten a full 8 steps later; R17 proved the store->recursion
//      register hazard: VMEM stores hold source VGPRs, +0.8 us at 4-wide).
// Word layout (signatory order): len1 cols 1..4, len2 cols 5..20,
// len3 cols 21..84, len4 cols 85..340; word (a,b,c,e) -> 85+64a+16b+4c+e.

#define SIG_B 32
#define SIG_L 512
#define SIG_NSTEP 511
#define SIG_ROW 341
#define SIG_CS 32            // chunk size (increments)
#define SIG_C 16             // chunks per batch
#define SIG_PAD 344          // padded row stride in workspace (floats, %4==0)

// ---------- Kernel A: local chunk signatures (R8 body, unchanged) ----------
__global__ __launch_bounds__(256) void sigA(const float* __restrict__ x,
                                            float* __restrict__ Lsig) {
    const int bc = blockIdx.x;
    const int b = bc / SIG_C, c = bc % SIG_C;
    const int tid = threadIdx.x;
    const int t0 = c * SIG_CS;
    const int nt = min(SIG_CS, SIG_NSTEP - t0);   // 32, or 31 for last chunk

    __shared__ float dlds[SIG_CS * 4];
    const float* xb = x + ((size_t)b * SIG_L + t0) * 4;
    if (tid < nt) {
        float4 x0 = *(const float4*)(xb + tid * 4);
        float4 x1 = *(const float4*)(xb + (tid + 1) * 4);
        *(float4*)(dlds + tid * 4) =
            make_float4(x1.x - x0.x, x1.y - x0.y, x1.z - x0.z, x1.w - x0.w);
    }
    __syncthreads();

    const int a = tid >> 6, bb = (tid >> 4) & 3, cc = (tid >> 2) & 3, ee = tid & 3;
    float s1 = 0.f, s2 = 0.f, s3 = 0.f, s4 = 0.f;
    const float* dp = dlds;
    for (int t = 0; t < nt; ++t) {
        const float da = dp[a], db = dp[bb], dc = dp[cc], de = dp[ee];
        dp += 4;
        s4 = fmaf(s3, de, s4);  // top level first: consumes pre-update s3
        s3 = fmaf(s2, dc, s3);
        s2 = fmaf(s1, db, s2);
        s1 += da;
    }
    float* Lr = Lsig + (size_t)bc * SIG_PAD;
    if ((tid & 63) == 0) Lr[1 + a] = s1;
    if ((tid & 15) == 0) Lr[5 + (tid >> 4)] = s2;
    if ((tid & 3) == 0)  Lr[21 + (tid >> 2)] = s3;
    Lr[85 + tid] = s4;
}

// ---------- Kernel C: unrolled combine + scan with 8-step store batching ----------
__global__ __launch_bounds__(256) void sigC(const float* __restrict__ x,
                                            const float* __restrict__ Lsig,
                                            float* __restrict__ out) {
    const int bc = blockIdx.x;
    const int b = bc / SIG_C, c = bc % SIG_C;
    const int tid = threadIdx.x;
    const int t0 = c * SIG_CS;
    const int nt = min(SIG_CS, SIG_NSTEP - t0);

    __shared__ float dlds[SIG_CS * 4];
    __shared__ float L[(SIG_C - 1) * SIG_PAD];   // 15 rows, rows >= c zeroed

    const float* xb = x + ((size_t)b * SIG_L + t0) * 4;
    if (tid < SIG_CS) {
        float4 d = make_float4(0.f, 0.f, 0.f, 0.f);   // zero-pad tail step
        if (tid < nt) {
            float4 x0 = *(const float4*)(xb + tid * 4);
            float4 x1 = *(const float4*)(xb + (tid + 1) * 4);
            d = make_float4(x1.x - x0.x, x1.y - x0.y, x1.z - x0.z, x1.w - x0.w);
        }
        *(float4*)(dlds + tid * 4) = d;
    }
    // Stage ALL 15 predecessor rows; zero-fill rows j>=c (Chen identity) so
    // the combine below is constant-trip and fully unrollable. Rows c..14 of
    // this batch exist in Lsig (other chunks' sigs), so the load is safe;
    // the select is one cndmask per float4, fully parallel, off the chain.
    {
        const float4* Lb4 = (const float4*)(Lsig + (size_t)b * SIG_C * SIG_PAD);
        float4* L4p = (float4*)L;
        const int nzero = c * (SIG_PAD / 4);      // float4s belonging to rows < c
        const int n4 = (SIG_C - 1) * (SIG_PAD / 4);
        for (int i = tid; i < n4; i += 256) {
            float4 v = Lb4[i];
            if (i >= nzero) v = make_float4(0.f, 0.f, 0.f, 0.f);
            L4p[i] = v;
        }
    }
    __syncthreads();

    const int a = tid >> 6, bb = (tid >> 4) & 3, cc = (tid >> 2) & 3, ee = tid & 3;

    // Chen-combine 15 rows (tail rows are zero = identity) -> prefix p1..p4.
    float p1 = 0.f, p2 = 0.f, p3 = 0.f, p4 = 0.f;
#pragma unroll
    for (int j = 0; j < SIG_C - 1; ++j) {
        const float* Lc = L + j * SIG_PAD;
        const float l1a = Lc[1 + a], l1b = Lc[1 + bb], l1c = Lc[1 + cc], l1e = Lc[1 + ee];
        const float l2ab = Lc[5 + 4 * a + bb], l2bc = Lc[5 + 4 * bb + cc],
                    l2ce = Lc[5 + 4 * cc + ee];
        const float l3abc = Lc[21 + 16 * a + 4 * bb + cc],
                    l3bce = Lc[21 + 16 * bb + 4 * cc + ee];
        const float l4 = Lc[85 + tid];
        p4 += p3 * l1e + p2 * l2ce + p1 * l3bce + l4;  // uses pre-update p1..p3
        p3 += p2 * l1c + p1 * l2bc + l3abc;
        p2 += p1 * l1b + l2ab;
        p1 += l1a;
    }

    float* row = out + ((size_t)b * SIG_L + (t0 + 1)) * SIG_ROW;

    if (c == 0) {  // row 0: [1, zeros]
        float* r0 = out + (size_t)b * SIG_L * SIG_ROW;
        if (tid == 0)        __builtin_nontemporal_store(1.0f, r0 + 0);
        if ((tid & 63) == 0) __builtin_nontemporal_store(0.f, r0 + 1 + a);
        if ((tid & 15) == 0) __builtin_nontemporal_store(0.f, r0 + 5 + (tid >> 4));
        if ((tid & 3) == 0)  __builtin_nontemporal_store(0.f, r0 + 21 + (tid >> 2));
        __builtin_nontemporal_store(0.f, r0 + 85 + tid);
    }

    // Scan with 8-step store batching: recursion runs 8 steps into snapshot
    // regs (static names -> renamed, no scratch), then 8 rows of stores.
    // Recursion registers are never sources of in-flight stores; snapshot
    // regs are rewritten a full 8 steps later.
    for (int tb = 0; tb < SIG_CS; tb += 8) {
        float o1_0, o2_0, o3_0, o4_0, o1_1, o2_1, o3_1, o4_1;
        float o1_2, o2_2, o3_2, o4_2, o1_3, o2_3, o3_3, o4_3;
        float o1_4, o2_4, o3_4, o4_4, o1_5, o2_5, o3_5, o4_5;
        float o1_6, o2_6, o3_6, o4_6, o1_7, o2_7, o3_7, o4_7;
#define SIG_STEP_SNAP(U, O1, O2, O3, O4)                                     \
        do {                                                                 \
            const float* dp_ = dlds + (tb + (U)) * 4;                        \
            const float da_ = dp_[a], db_ = dp_[bb],                         \
                        dc_ = dp_[cc], de_ = dp_[ee];                        \
            p4 = fmaf(p3, de_, p4);  /* pre-update lower levels */           \
            p3 = fmaf(p2, dc_, p3);                                          \
            p2 = fmaf(p1, db_, p2);                                          \
            p1 += da_;                                                       \
            O1 = p1; O2 = p2; O3 = p3; O4 = p4;                              \
        } while (0)
        SIG_STEP_SNAP(0, o1_0, o2_0, o3_0, o4_0);
        SIG_STEP_SNAP(1, o1_1, o2_1, o3_1, o4_1);
        SIG_STEP_SNAP(2, o1_2, o2_2, o3_2, o4_2);
        SIG_STEP_SNAP(3, o1_3, o2_3, o3_3, o4_3);
        SIG_STEP_SNAP(4, o1_4, o2_4, o3_4, o4_4);
        SIG_STEP_SNAP(5, o1_5, o2_5, o3_5, o4_5);
        SIG_STEP_SNAP(6, o1_6, o2_6, o3_6, o4_6);
        SIG_STEP_SNAP(7, o1_7, o2_7, o3_7, o4_7);
#undef SIG_STEP_SNAP

#define SIG_STORE_ROW(U, O1, O2, O3, O4)                                     \
        do {                                                                 \
            if (tb + (U) < nt) {                                             \
                float* r_ = row + (size_t)(tb + (U)) * SIG_ROW;              \
                if (tid == 0)                                                \
                    __builtin_nontemporal_store(1.0f, r_ + 0);               \
                if ((tid & 63) == 0)                                         \
                    __builtin_nontemporal_store(O1, r_ + 1 + a);             \
                if ((tid & 15) == 0)                                         \
                    __builtin_nontemporal_store(O2, r_ + 5 + (tid >> 4));    \
                if ((tid & 3) == 0)                                          \
                    __builtin_nontemporal_store(O3, r_ + 21 + (tid >> 2));   \
                __builtin_nontemporal_store(O4, r_ + 85 + tid);              \
            }                                                                \
        } while (0)
        SIG_STORE_ROW(0, o1_0, o2_0, o3_0, o4_0);
        SIG_STORE_ROW(1, o1_1, o2_1, o3_1, o4_1);
        SIG_STORE_ROW(2, o1_2, o2_2, o3_2, o4_2);
        SIG_STORE_ROW(3, o1_3, o2_3, o3_3, o4_3);
        SIG_STORE_ROW(4, o1_4, o2_4, o3_4, o4_4);
        SIG_STORE_ROW(5, o1_5, o2_5, o3_5, o4_5);
        SIG_STORE_ROW(6, o1_6, o2_6, o3_6, o4_6);
        SIG_STORE_ROW(7, o1_7, o2_7, o3_7, o4_7);
#undef SIG_STORE_ROW
    }
}

extern "C" void kernel_launch(void* const* d_in, const int* in_sizes, int n_in,
                              void* d_out, int out_size, void* d_ws, size_t ws_size,
                              hipStream_t stream) {
    const float* x = (const float*)d_in[0];   // (32, 512, 4) f32
    float* out = (float*)d_out;               // (32, 512, 341) f32
    float* Lsig = (float*)d_ws;               // 512 * 344 floats

    sigA<<<SIG_B * SIG_C, 256, 0, stream>>>(x, Lsig);
    sigC<<<SIG_B * SIG_C, 256, 0, stream>>>(x, Lsig, out);
}

// Round 19
// 20.614 us; speedup vs baseline: 1.0138x; 1.0138x over previous
//
#include <hip/hip_runtime.h>

// GrowingSignature: truncated iterated-sums signature, levels 1..4, F=4.
// x: (32, 512, 4) f32;  out: (32, 512, 341) f32.
// R19 = R17 champion (4-step store batching) + ONE change: constant-trip-15
// combine (rows j>=c zero-filled at staging; zeros = Chen identity) so the
// combine fully unrolls and its LDS reads pipeline off the serial FMA chain.
// Isolates R18's bundle (which also changed batching 4->8 and was +0.3).
// R17 finding kept: VMEM stores hold source VGPRs -> batch 4 steps into
// snapshot regs so the recursion never waits on in-flight stores.
// Word layout (signatory order): len1 cols 1..4, len2 cols 5..20,
// len3 cols 21..84, len4 cols 85..340; word (a,b,c,e) -> 85+64a+16b+4c+e.

#define SIG_B 32
#define SIG_L 512
#define SIG_NSTEP 511
#define SIG_ROW 341
#define SIG_CS 32            // chunk size (increments)
#define SIG_C 16             // chunks per batch
#define SIG_PAD 344          // padded row stride in workspace (floats, %4==0)

// ---------- Kernel A: local chunk signatures (R8 body, unchanged) ----------
__global__ __launch_bounds__(256) void sigA(const float* __restrict__ x,
                                            float* __restrict__ Lsig) {
    const int bc = blockIdx.x;
    const int b = bc / SIG_C, c = bc % SIG_C;
    const int tid = threadIdx.x;
    const int t0 = c * SIG_CS;
    const int nt = min(SIG_CS, SIG_NSTEP - t0);   // 32, or 31 for last chunk

    __shared__ float dlds[SIG_CS * 4];
    const float* xb = x + ((size_t)b * SIG_L + t0) * 4;
    if (tid < nt) {
        float4 x0 = *(const float4*)(xb + tid * 4);
        float4 x1 = *(const float4*)(xb + (tid + 1) * 4);
        *(float4*)(dlds + tid * 4) =
            make_float4(x1.x - x0.x, x1.y - x0.y, x1.z - x0.z, x1.w - x0.w);
    }
    __syncthreads();

    const int a = tid >> 6, bb = (tid >> 4) & 3, cc = (tid >> 2) & 3, ee = tid & 3;
    float s1 = 0.f, s2 = 0.f, s3 = 0.f, s4 = 0.f;
    const float* dp = dlds;
    for (int t = 0; t < nt; ++t) {
        const float da = dp[a], db = dp[bb], dc = dp[cc], de = dp[ee];
        dp += 4;
        s4 = fmaf(s3, de, s4);  // top level first: consumes pre-update s3
        s3 = fmaf(s2, dc, s3);
        s2 = fmaf(s1, db, s2);
        s1 += da;
    }
    float* Lr = Lsig + (size_t)bc * SIG_PAD;
    if ((tid & 63) == 0) Lr[1 + a] = s1;
    if ((tid & 15) == 0) Lr[5 + (tid >> 4)] = s2;
    if ((tid & 3) == 0)  Lr[21 + (tid >> 2)] = s3;
    Lr[85 + tid] = s4;
}

// ---------- Kernel C: unrolled combine + scan with 4-step store batching ----------
__global__ __launch_bounds__(256) void sigC(const float* __restrict__ x,
                                            const float* __restrict__ Lsig,
                                            float* __restrict__ out) {
    const int bc = blockIdx.x;
    const int b = bc / SIG_C, c = bc % SIG_C;
    const int tid = threadIdx.x;
    const int t0 = c * SIG_CS;
    const int nt = min(SIG_CS, SIG_NSTEP - t0);

    __shared__ float dlds[SIG_CS * 4];
    __shared__ float L[(SIG_C - 1) * SIG_PAD];   // 15 rows, rows >= c zeroed

    const float* xb = x + ((size_t)b * SIG_L + t0) * 4;
    if (tid < SIG_CS) {
        float4 d = make_float4(0.f, 0.f, 0.f, 0.f);   // zero-pad tail step
        if (tid < nt) {
            float4 x0 = *(const float4*)(xb + tid * 4);
            float4 x1 = *(const float4*)(xb + (tid + 1) * 4);
            d = make_float4(x1.x - x0.x, x1.y - x0.y, x1.z - x0.z, x1.w - x0.w);
        }
        *(float4*)(dlds + tid * 4) = d;
    }
    // Stage ALL 15 predecessor rows; zero-fill rows j>=c (Chen identity) so
    // the combine below is constant-trip and fully unrollable. The select is
    // one cndmask per float4 at staging time — parallel, off the serial chain.
    {
        const float4* Lb4 = (const float4*)(Lsig + (size_t)b * SIG_C * SIG_PAD);
        float4* L4p = (float4*)L;
        const int nzero = c * (SIG_PAD / 4);      // float4s belonging to rows < c
        const int n4 = (SIG_C - 1) * (SIG_PAD / 4);
        for (int i = tid; i < n4; i += 256) {
            float4 v = Lb4[i];
            if (i >= nzero) v = make_float4(0.f, 0.f, 0.f, 0.f);
            L4p[i] = v;
        }
    }
    __syncthreads();

    const int a = tid >> 6, bb = (tid >> 4) & 3, cc = (tid >> 2) & 3, ee = tid & 3;

    // Chen-combine 15 rows (tail rows are zero = identity) -> prefix p1..p4.
    float p1 = 0.f, p2 = 0.f, p3 = 0.f, p4 = 0.f;
#pragma unroll
    for (int j = 0; j < SIG_C - 1; ++j) {
        const float* Lc = L + j * SIG_PAD;
        const float l1a = Lc[1 + a], l1b = Lc[1 + bb], l1c = Lc[1 + cc], l1e = Lc[1 + ee];
        const float l2ab = Lc[5 + 4 * a + bb], l2bc = Lc[5 + 4 * bb + cc],
                    l2ce = Lc[5 + 4 * cc + ee];
        const float l3abc = Lc[21 + 16 * a + 4 * bb + cc],
                    l3bce = Lc[21 + 16 * bb + 4 * cc + ee];
        const float l4 = Lc[85 + tid];
        p4 += p3 * l1e + p2 * l2ce + p1 * l3bce + l4;  // uses pre-update p1..p3
        p3 += p2 * l1c + p1 * l2bc + l3abc;
        p2 += p1 * l1b + l2ab;
        p1 += l1a;
    }

    float* row = out + ((size_t)b * SIG_L + (t0 + 1)) * SIG_ROW;

    if (c == 0) {  // row 0: [1, zeros]
        float* r0 = out + (size_t)b * SIG_L * SIG_ROW;
        if (tid == 0)        __builtin_nontemporal_store(1.0f, r0 + 0);
        if ((tid & 63) == 0) __builtin_nontemporal_store(0.f, r0 + 1 + a);
        if ((tid & 15) == 0) __builtin_nontemporal_store(0.f, r0 + 5 + (tid >> 4));
        if ((tid & 3) == 0)  __builtin_nontemporal_store(0.f, r0 + 21 + (tid >> 2));
        __builtin_nontemporal_store(0.f, r0 + 85 + tid);
    }

    // Scan with 4-step store batching (R17): recursion runs 4 steps into
    // snapshot regs (static names -> renamed, no scratch), then 4 rows of
    // stores. Recursion registers are never sources of in-flight stores.
    for (int tb = 0; tb < SIG_CS; tb += 4) {
        float o1_0, o2_0, o3_0, o4_0, o1_1, o2_1, o3_1, o4_1;
        float o1_2, o2_2, o3_2, o4_2, o1_3, o2_3, o3_3, o4_3;
#define SIG_STEP_SNAP(U, O1, O2, O3, O4)                                     \
        do {                                                                 \
            const float* dp_ = dlds + (tb + (U)) * 4;                        \
            const float da_ = dp_[a], db_ = dp_[bb],                         \
                        dc_ = dp_[cc], de_ = dp_[ee];                        \
            p4 = fmaf(p3, de_, p4);  /* pre-update lower levels */           \
            p3 = fmaf(p2, dc_, p3);                                          \
            p2 = fmaf(p1, db_, p2);                                          \
            p1 += da_;                                                       \
            O1 = p1; O2 = p2; O3 = p3; O4 = p4;                              \
        } while (0)
        SIG_STEP_SNAP(0, o1_0, o2_0, o3_0, o4_0);
        SIG_STEP_SNAP(1, o1_1, o2_1, o3_1, o4_1);
        SIG_STEP_SNAP(2, o1_2, o2_2, o3_2, o4_2);
        SIG_STEP_SNAP(3, o1_3, o2_3, o3_3, o4_3);
#undef SIG_STEP_SNAP

#define SIG_STORE_ROW(U, O1, O2, O3, O4)                                     \
        do {                                                                 \
            if (tb + (U) < nt) {                                             \
                float* r_ = row + (size_t)(tb + (U)) * SIG_ROW;              \
                if (tid == 0)                                                \
                    __builtin_nontemporal_store(1.0f, r_ + 0);               \
                if ((tid & 63) == 0)                                         \
                    __builtin_nontemporal_store(O1, r_ + 1 + a);             \
                if ((tid & 15) == 0)                                         \
                    __builtin_nontemporal_store(O2, r_ + 5 + (tid >> 4));    \
                if ((tid & 3) == 0)                                          \
                    __builtin_nontemporal_store(O3, r_ + 21 + (tid >> 2));   \
                __builtin_nontemporal_store(O4, r_ + 85 + tid);              \
            }                                                                \
        } while (0)
        SIG_STORE_ROW(0, o1_0, o2_0, o3_0, o4_0);
        SIG_STORE_ROW(1, o1_1, o2_1, o3_1, o4_1);
        SIG_STORE_ROW(2, o1_2, o2_2, o3_2, o4_2);
        SIG_STORE_ROW(3, o1_3, o2_3, o3_3, o4_3);
#undef SIG_STORE_ROW
    }
}

extern "C" void kernel_launch(void* const* d_in, const int* in_sizes, int n_in,
                              void* d_out, int out_size, void* d_ws, size_t ws_size,
                              hipStream_t stream) {
    const float* x = (const float*)d_in[0];   // (32, 512, 4) f32
    float* out = (float*)d_out;               // (32, 512, 341) f32
    float* Lsig = (float*)d_ws;               // 512 * 344 floats

    sigA<<<SIG_B * SIG_C, 256, 0, stream>>>(x, Lsig);
    sigC<<<SIG_B * SIG_C, 256, 0, stream>>>(x, Lsig, out);
}